// Round 1
// baseline (1979.383 us; speedup 1.0000x reference)
//
#include <hip/hip_runtime.h>

#define L_LEN 512
#define D_DIM 4096
#define H_NUM 8
#define B_NUM 16
#define TOPK  12
#define CPW   8   // channels per workgroup in stage A (one wave each)

// ---------------------------------------------------------------------------
// Stage A: per-channel circular cross-correlation + top-12 + softmax
// grid = B*H*(512/CPW) = 8192 blocks of 512 threads (8 waves)
// Each wave handles one channel: lane l owns tau = 8l..8l+7.
// q is staged duplicated (1024 words) with an XOR bank swizzle
// (bits[4:2] ^= bits[7:5]) so stride-8-word lane access is ~conflict-free
// while keeping 4-word groups contiguous for float4 LDS reads.
// ---------------------------------------------------------------------------
__global__ __launch_bounds__(512) void corr_topk_kernel(
    const float* __restrict__ Q, const float* __restrict__ K,
    float* __restrict__ ws_w, int* __restrict__ ws_i)
{
  __shared__ float qs[CPW][1024];
  __shared__ float ks[CPW][512];

  const int tid  = threadIdx.x;
  const int wg   = blockIdx.x;
  const int cblk = wg & 63;        // 512/CPW = 64 channel-blocks per (b,h)
  const int bh   = wg >> 6;        // b*8 + h
  const int c0   = cblk * CPW;

  const size_t base = (size_t)(bh >> 3) * (L_LEN * D_DIM)
                    + (size_t)(bh & 7) * 512 + c0;

  // stage Q,K: q[t][c], k[t][c] for t in [0,512), c in [c0,c0+8)
  {
    const int c  = tid & (CPW - 1);
    const int t0 = tid >> 3;                 // 0..63
    #pragma unroll
    for (int rep = 0; rep < 8; ++rep) {
      const int t  = t0 + rep * 64;
      const float qv = Q[base + (size_t)t * D_DIM + c];
      const float kv = K[base + (size_t)t * D_DIM + c];
      const int sw = t ^ (((t >> 5) & 7) << 2);   // XOR swizzle
      qs[c][sw]       = qv;
      qs[c][sw + 512] = qv;    // swz(t+512) == swz(t)+512 (bit9 unused)
      ks[c][t] = kv;
    }
  }
  __syncthreads();

  const int wave = tid >> 6;     // 0..7 -> channel c0+wave
  const int lane = tid & 63;
  const float* qc = qs[wave];
  const float* kc = ks[wave];

  float acc[8];
  #pragma unroll
  for (int i = 0; i < 8; ++i) acc[i] = 0.f;

  const int tau0 = lane * 8;

  #pragma unroll 1
  for (int t0 = 0; t0 < 512; t0 += 8) {
    const float4 k01 = *(const float4*)(kc + t0);       // wave-uniform: broadcast
    const float4 k23 = *(const float4*)(kc + t0 + 4);
    float q16[16];
    #pragma unroll
    for (int m = 0; m < 4; ++m) {
      const int w  = t0 + tau0 + 4 * m;                 // 4-aligned logical word
      const int sw = w ^ (((w >> 5) & 7) << 2);         // swizzled, still 4-aligned
      const float4 qv = *(const float4*)(qc + sw);
      q16[4*m+0] = qv.x; q16[4*m+1] = qv.y; q16[4*m+2] = qv.z; q16[4*m+3] = qv.w;
    }
    const float k8[8] = {k01.x,k01.y,k01.z,k01.w,k23.x,k23.y,k23.z,k23.w};
    #pragma unroll
    for (int i = 0; i < 8; ++i)
      #pragma unroll
      for (int j = 0; j < 8; ++j)
        acc[i] = fmaf(q16[i + j], k8[j], acc[i]);
  }
  // acc[i] = corr[tau0+i] for this wave's channel

  // ---- top-12 via repeated wave argmax (tie-break: smaller index, like jax)
  float bv[12]; int bi[12];
  #pragma unroll
  for (int s = 0; s < TOPK; ++s) {
    float lv = acc[0]; int li = 0;
    #pragma unroll
    for (int i = 1; i < 8; ++i) if (acc[i] > lv) { lv = acc[i]; li = i; }
    int gi = tau0 + li;
    #pragma unroll
    for (int off = 32; off >= 1; off >>= 1) {
      const float ov = __shfl_xor(lv, off);
      const int   oi = __shfl_xor(gi, off);
      if (ov > lv || (ov == lv && oi < gi)) { lv = ov; gi = oi; }
    }
    bv[s] = lv; bi[s] = gi;
    const int slot = gi - tau0;              // 0..7 only on the owning lane
    #pragma unroll
    for (int i = 0; i < 8; ++i) acc[i] = (slot == i) ? -3.4e38f : acc[i];
  }

  // ---- softmax over the 12 (bv[0] is the max), redundant on all lanes
  float e[12]; float sum = 0.f;
  #pragma unroll
  for (int s = 0; s < TOPK; ++s) { e[s] = expf(bv[s] - bv[0]); sum += e[s]; }
  const float inv = 1.f / sum;

  if (lane == 0) {
    const int g = (bh * 512 + c0 + wave) * TOPK;
    #pragma unroll
    for (int s = 0; s < TOPK; ++s) { ws_w[g + s] = e[s] * inv; ws_i[g + s] = bi[s]; }
  }
}

// ---------------------------------------------------------------------------
// Stage B: out[b,t,dpos] = sum_s w_s * V[b, min(idx_s+t,511), dpos]
// Lanes along dpos (coalesced writes); 16-t loop amortizes w/idx loads.
// grid = B * (512/16) * (4096/256) = 8192 blocks of 256 threads
// ---------------------------------------------------------------------------
__global__ __launch_bounds__(256) void gather_kernel(
    const float* __restrict__ V, const float* __restrict__ ws_w,
    const int* __restrict__ ws_i, float* __restrict__ out)
{
  const int tid  = threadIdx.x;
  const int blk  = blockIdx.x;           // b*(32*16) + tblk*16 + dgrp
  const int dgrp = blk & 15;
  const int tblk = (blk >> 4) & 31;
  const int b    = blk >> 9;
  const int dpos = dgrp * 256 + tid;
  const int g    = (b * D_DIM + dpos) * TOPK;

  float w[TOPK]; int r0[TOPK];
  #pragma unroll
  for (int s = 0; s < TOPK; ++s) { w[s] = ws_w[g + s]; r0[s] = ws_i[g + s]; }

  const float* vb = V   + ((size_t)b << 21);   // b*512*4096
  float*       ob = out + ((size_t)b << 21) + dpos;

  #pragma unroll 1
  for (int j = 0; j < 16; ++j) {
    const int t = tblk * 16 + j;
    float acc = 0.f;
    #pragma unroll
    for (int s = 0; s < TOPK; ++s) {
      int r = r0[s] + t;
      r = r > (L_LEN - 1) ? (L_LEN - 1) : r;
      acc = fmaf(w[s], vb[((size_t)r << 12) + dpos], acc);
    }
    ob[(size_t)t << 12] = acc;
  }
}

extern "C" void kernel_launch(void* const* d_in, const int* in_sizes, int n_in,
                              void* d_out, int out_size, void* d_ws, size_t ws_size,
                              hipStream_t stream)
{
  const float* Q = (const float*)d_in[0];
  const float* K = (const float*)d_in[1];
  const float* V = (const float*)d_in[2];
  float* out = (float*)d_out;

  // workspace: 65536 channels * 12 * (float w + int idx) = 6 MB
  float* ws_w = (float*)d_ws;
  int*   ws_i = (int*)((char*)d_ws + (size_t)B_NUM * H_NUM * 512 * TOPK * sizeof(float));

  corr_topk_kernel<<<dim3(B_NUM * H_NUM * 64), dim3(512), 0, stream>>>(Q, K, ws_w, ws_i);
  gather_kernel<<<dim3(B_NUM * 32 * 16), dim3(256), 0, stream>>>(V, ws_w, ws_i, out);
}

// Round 2
// 897.546 us; speedup vs baseline: 2.2053x; 2.2053x over previous
//
#include <hip/hip_runtime.h>

#define L_LEN 512
#define D_DIM 4096
#define H_NUM 8
#define B_NUM 16
#define TOPK  12
#define CPW   8      // channels per workgroup in stage A (one wave each)
#define QROW 1056    // 512 + 512 dup + 32 wrap + slack, multiple of 32

// Swizzle: XOR bit5 into bit2. Lane-stride-8 access patterns toggle bit5
// every 4 lanes (carry-robust), so each 8-lane cohort covers all 8
// 16B bank-groups -> conflict-free ds_read_b128. swz(t+512)=swz(t)+512.
__device__ __forceinline__ int swz(int w) { return w ^ (((w >> 5) & 1) << 2); }

// ---------------------------------------------------------------------------
// Stage A: per-channel circular cross-correlation + top-12 + softmax
// grid = B*H*64 blocks of 512 threads; one wave per channel;
// lane l owns tau = 8l..8l+7 with sliding-window q reuse in registers.
// ---------------------------------------------------------------------------
__global__ __launch_bounds__(512) void corr_topk_kernel(
    const float* __restrict__ Q, const float* __restrict__ K,
    float* __restrict__ ws_w, int* __restrict__ ws_i)
{
  __shared__ float qs[CPW][QROW];   // 33792 B
  __shared__ float ks[CPW][512];    // 16384 B

  const int tid  = threadIdx.x;
  const int wg   = blockIdx.x;
  const int cblk = wg & 63;
  const int bh   = wg >> 6;
  const int c0   = cblk * CPW;

  const size_t base = (size_t)(bh >> 3) * (L_LEN * D_DIM)
                    + (size_t)(bh & 7) * 512 + c0;

  // ---- staging: thread loads float4 = 4 channels of one row t.
  // LDS write banks: sw&31 = (lane>>1)^const -> 32 distinct, 2 lanes/bank (free)
  #pragma unroll
  for (int rep = 0; rep < 2; ++rep) {
    const int idx  = rep * 512 + tid;       // 0..1023
    const int t    = idx >> 1;              // 0..511
    const int half = idx & 1;               // which 4-channel quad
    const float4 qv = *(const float4*)(Q + base + (size_t)t * D_DIM + half * 4);
    const float4 kv = *(const float4*)(K + base + (size_t)t * D_DIM + half * 4);
    const int sw = swz(t);
    const int cb = half * 4;
    const float qa[4] = {qv.x, qv.y, qv.z, qv.w};
    const float ka[4] = {kv.x, kv.y, kv.z, kv.w};
    #pragma unroll
    for (int j = 0; j < 4; ++j) {
      qs[cb + j][sw]       = qa[j];
      qs[cb + j][sw + 512] = qa[j];         // swz(t+512) == swz(t)+512
      ks[cb + j][t]        = ka[j];
    }
    if (t < 32) {                           // third wrap copy, region [1024,1056)
      #pragma unroll
      for (int j = 0; j < 4; ++j) qs[cb + j][1024 + t] = qa[j];
    }
  }
  __syncthreads();

  const int wave = tid >> 6;
  const int lane = tid & 63;
  const float* qc = qs[wave];
  const float* kc = ks[wave];
  const int tau0 = lane * 8;

  float acc[8];
  #pragma unroll
  for (int i = 0; i < 8; ++i) acc[i] = 0.f;

  #define LDQ(x) (*(const float4*)(qc + swz(tau0 + (x))))
  #define MAC8(A0,A1,A2,A3,K0,K1) do {                                      \
    const float q16[16] = {A0.x,A0.y,A0.z,A0.w, A1.x,A1.y,A1.z,A1.w,        \
                           A2.x,A2.y,A2.z,A2.w, A3.x,A3.y,A3.z,A3.w};       \
    const float k8[8]   = {K0.x,K0.y,K0.z,K0.w, K1.x,K1.y,K1.z,K1.w};       \
    _Pragma("unroll")                                                       \
    for (int i = 0; i < 8; ++i)                                             \
      _Pragma("unroll")                                                     \
      for (int j = 0; j < 8; ++j)                                           \
        acc[i] = fmaf(q16[i + j], k8[j], acc[i]);                           \
  } while (0)

  float4 p0 = LDQ(0), p1 = LDQ(4), p2 = LDQ(8), p3 = LDQ(12);
  #pragma unroll 1
  for (int t0 = 0; t0 < 512; t0 += 16) {
    const float4 k0 = *(const float4*)(kc + t0);
    const float4 k1 = *(const float4*)(kc + t0 + 4);
    const float4 p4 = LDQ(t0 + 16);
    const float4 p5 = LDQ(t0 + 20);
    MAC8(p0, p1, p2, p3, k0, k1);
    const float4 k2 = *(const float4*)(kc + t0 + 8);
    const float4 k3 = *(const float4*)(kc + t0 + 12);
    const float4 p6 = LDQ(t0 + 24);
    const float4 p7 = LDQ(t0 + 28);
    MAC8(p2, p3, p4, p5, k2, k3);
    p0 = p4; p1 = p5; p2 = p6; p3 = p7;
  }

  // ---- top-12 via repeated wave argmax (tie-break: smaller index)
  float bv[TOPK]; int bi[TOPK];
  #pragma unroll
  for (int s = 0; s < TOPK; ++s) {
    float lv = acc[0]; int li = 0;
    #pragma unroll
    for (int i = 1; i < 8; ++i) if (acc[i] > lv) { lv = acc[i]; li = i; }
    int gi = tau0 + li;
    #pragma unroll
    for (int off = 32; off >= 1; off >>= 1) {
      const float ov = __shfl_xor(lv, off);
      const int   oi = __shfl_xor(gi, off);
      if (ov > lv || (ov == lv && oi < gi)) { lv = ov; gi = oi; }
    }
    bv[s] = lv; bi[s] = gi;
    const int slot = gi - tau0;
    #pragma unroll
    for (int i = 0; i < 8; ++i) acc[i] = (slot == i) ? -3.4e38f : acc[i];
  }

  float e[TOPK]; float sum = 0.f;
  #pragma unroll
  for (int s = 0; s < TOPK; ++s) { e[s] = expf(bv[s] - bv[0]); sum += e[s]; }
  const float inv = 1.f / sum;

  if (lane == 0) {
    const int g = (bh * 512 + c0 + wave) * TOPK;
    #pragma unroll
    for (int s = 0; s < TOPK; ++s) { ws_w[g + s] = e[s] * inv; ws_i[g + s] = bi[s]; }
  }
}

// ---------------------------------------------------------------------------
// Stage B: block = (b, h, 32-channel group). Stage V[:,cg] tile in LDS
// (coalesced 128B global reads), gather from LDS (bank = lane&31 exactly ->
// conflict-free), coalesced writes.
// grid = 16*8*16 = 2048 blocks of 256 threads
// ---------------------------------------------------------------------------
__global__ __launch_bounds__(256) void gather_kernel(
    const float* __restrict__ V, const float* __restrict__ ws_w,
    const int* __restrict__ ws_i, float* __restrict__ out)
{
  __shared__ float vs[512][32];     // 65536 B

  const int tid = threadIdx.x;
  const int bid = blockIdx.x;
  const int cg  = bid & 15;
  const int h   = (bid >> 4) & 7;
  const int b   = bid >> 7;
  const size_t vbase = ((size_t)b << 21) + h * 512 + cg * 32;

  // stage V tile: lanes 0-7 read one full 128B row segment
  #pragma unroll
  for (int rep = 0; rep < 16; ++rep) {
    const int idx = rep * 256 + tid;        // 0..4095
    const int t   = idx >> 3;
    const int q   = idx & 7;
    const float4 v4 = *(const float4*)(V + vbase + (size_t)t * D_DIM + q * 4);
    *(float4*)(&vs[t][q * 4]) = v4;
  }

  const int c_loc = tid & 31;
  const int tsub  = tid >> 5;
  const int g = ((b * 8 + h) * 512 + cg * 32 + c_loc) * TOPK;

  float w[TOPK]; int r0[TOPK];
  #pragma unroll
  for (int s = 0; s < TOPK; ++s) { w[s] = ws_w[g + s]; r0[s] = ws_i[g + s]; }

  __syncthreads();

  float* op = out + vbase + c_loc;
  #pragma unroll 1
  for (int t = tsub; t < 512; t += 8) {
    float a = 0.f;
    #pragma unroll
    for (int s = 0; s < TOPK; ++s) {
      int r = r0[s] + t;
      r = r > (L_LEN - 1) ? (L_LEN - 1) : r;
      a = fmaf(w[s], vs[r][c_loc], a);
    }
    op[(size_t)t * D_DIM] = a;
  }
}

extern "C" void kernel_launch(void* const* d_in, const int* in_sizes, int n_in,
                              void* d_out, int out_size, void* d_ws, size_t ws_size,
                              hipStream_t stream)
{
  const float* Q = (const float*)d_in[0];
  const float* K = (const float*)d_in[1];
  const float* V = (const float*)d_in[2];
  float* out = (float*)d_out;

  float* ws_w = (float*)d_ws;
  int*   ws_i = (int*)((char*)d_ws + (size_t)B_NUM * H_NUM * 512 * TOPK * sizeof(float));

  corr_topk_kernel<<<dim3(B_NUM * H_NUM * 64), dim3(512), 0, stream>>>(Q, K, ws_w, ws_i);
  gather_kernel<<<dim3(B_NUM * H_NUM * 16), dim3(256), 0, stream>>>(V, ws_w, ws_i, out);
}